// Round 3
// baseline (81.550 us; speedup 1.0000x reference)
//
#include <hip/hip_runtime.h>

#define BATCH 262144
#define HALF  (BATCH / 2)
#define BLOCK 256

// ---------- scalar complex (setup only) ----------
struct c2f { float re, im; };
__device__ __forceinline__ c2f cmul(c2f a, c2f b){
    return { a.re*b.re - a.im*b.im, a.re*b.im + a.im*b.re };
}
__device__ __forceinline__ c2f cmulc(c2f a, c2f b){  // a * conj(b)
    return { a.re*b.re + a.im*b.im, a.im*b.re - a.re*b.im };
}
__device__ __forceinline__ void su2mul(c2f a1, c2f b1, c2f a2, c2f b2, c2f& ao, c2f& bo){
    c2f t1 = cmul(a1, a2), t2 = cmulc(b1, b2);
    ao = { t1.re - t2.re, t1.im - t2.im };
    c2f t3 = cmul(a1, b2), t4 = cmulc(b1, a2);
    bo = { t3.re + t4.re, t3.im + t4.im };
}
__device__ __forceinline__ int czneg(int s){
    int b0 = (s >> 3) & 1, b1 = (s >> 2) & 1, b2 = (s >> 1) & 1, b3 = s & 1;
    return (b0 & b1) ^ (b1 & b2) ^ (b2 & b3) ^ (b0 & b3);
}

// ---------- packed pair-of-batch-elements math (v_pk_* friendly) ----------
struct p2 { float x, y; };
__device__ __forceinline__ p2 operator+(p2 a, p2 b){ return { a.x + b.x, a.y + b.y }; }
__device__ __forceinline__ p2 operator-(p2 a, p2 b){ return { a.x - b.x, a.y - b.y }; }
__device__ __forceinline__ p2 operator*(p2 a, p2 b){ return { a.x * b.x, a.y * b.y }; }
__device__ __forceinline__ p2 operator-(p2 a){ return { -a.x, -a.y }; }
__device__ __forceinline__ p2 splat(float f){ return { f, f }; }

struct cp { p2 re, im; };
__device__ __forceinline__ cp cpmul(cp a, cp b){
    return { a.re*b.re - a.im*b.im, a.re*b.im + a.im*b.re };
}
__device__ __forceinline__ cp cpmulc(cp a, cp b){
    return { a.re*b.re + a.im*b.im, a.im*b.re - a.re*b.im };
}
__device__ __forceinline__ void su2mulp(cp a1, cp b1, cp a2, cp b2, cp& ao, cp& bo){
    cp t1 = cpmul(a1, a2), t2 = cpmulc(b1, b2);
    ao = { t1.re - t2.re, t1.im - t2.im };
    cp t3 = cpmul(a1, b2), t4 = cpmulc(b1, a2);
    bo = { t3.re + t4.re, t3.im + t4.im };
}

#define INV2PI 0.15915494309189535f

__global__ __launch_bounds__(BLOCK) void vqc_kernel(
    const float* __restrict__ x,      // (BATCH,4) f32
    const float* __restrict__ theta,  // 48 f32
    const float* __restrict__ lmbd,   // 12 f32
    float* __restrict__ out)          // (BATCH,4) f32
{
    // --- per-block precompute of batch-independent SU(2) factors ---
    __shared__ float2 sU[4][4][2];   // [param layer][qubit][alpha,beta]
    __shared__ float2 sA[3][4][2];   // A^(0)=U1*W, A^(1)=U2*W, A^(2)=W (W=U3)
    __shared__ float2 sPsi0[16];     // CZ * (tensor U^(0)) |0>
    __shared__ float  sRev[12];      // 0.5 * lmbd / (2*pi)

    const int tid = threadIdx.x;

    if (tid < 16) {
        int l = tid >> 2, q = tid & 3;
        float t0 = 0.5f * theta[(l * 4 + q) * 3 + 0];
        float t1 = 0.5f * theta[(l * 4 + q) * 3 + 1];
        float t2 = 0.5f * theta[(l * 4 + q) * 3 + 2];
        float c0, s0, c1, s1, c2v, s2v;
        __sincosf(t0, &s0, &c0);
        __sincosf(t1, &s1, &c1);
        __sincosf(t2, &s2v, &c2v);
        c2f aP = { c1 * c0, s1 * s0 };
        c2f bP = { -s1 * c0, -c1 * s0 };
        c2f ph = { c2v, -s2v };
        c2f aU = cmul(ph, aP);
        c2f bU = cmul(ph, bP);
        sU[l][q][0] = make_float2(aU.re, aU.im);
        sU[l][q][1] = make_float2(bU.re, bU.im);
    }
    if (tid < 12) sRev[tid] = (0.5f * INV2PI) * lmbd[tid];
    __syncthreads();

    if (tid < 12) {
        int k = tid >> 2, q = tid & 3;
        c2f aW = { sU[3][q][0].x, sU[3][q][0].y };
        c2f bW = { sU[3][q][1].x, sU[3][q][1].y };
        c2f aA = aW, bA = bW;
        if (k < 2) {
            c2f aN = { sU[k + 1][q][0].x, sU[k + 1][q][0].y };
            c2f bN = { sU[k + 1][q][1].x, sU[k + 1][q][1].y };
            su2mul(aN, bN, aW, bW, aA, bA);   // U^(k+1) * W
        }
        sA[k][q][0] = make_float2(aA.re, aA.im);
        sA[k][q][1] = make_float2(bA.re, bA.im);
    }
    if (tid >= 16 && tid < 32) {
        int s = tid - 16;
        c2f v = { 1.f, 0.f };
        #pragma unroll
        for (int q = 0; q < 4; ++q) {
            int bit = (s >> (3 - q)) & 1;
            c2f a = { sU[0][q][0].x, sU[0][q][0].y };
            c2f b = { sU[0][q][1].x, sU[0][q][1].y };
            c2f e = bit ? c2f{ -b.re, b.im } : a;
            v = cmul(v, e);
        }
        if (czneg(s)) { v.re = -v.re; v.im = -v.im; }
        sPsi0[s] = make_float2(v.re, v.im);
    }
    __syncthreads();

    // --- per-thread: 2 batch elements packed as (x,y) of p2 ---
    const int t = blockIdx.x * BLOCK + tid;     // 0 .. HALF-1
    float4 xa = ((const float4*)x)[t];
    float4 xb = ((const float4*)x)[t + HALF];
    p2 xv[4] = { {xa.x, xb.x}, {xa.y, xb.y}, {xa.z, xb.z}, {xa.w, xb.w} };

    p2 prr[16], pii[16];
    #pragma unroll
    for (int s = 0; s < 16; ++s) {
        float2 v = sPsi0[s];
        prr[s] = splat(v.x);
        pii[s] = splat(v.y);
    }

    #pragma unroll
    for (int k = 0; k < 3; ++k) {
        p2 ch[4], sh[4];
        #pragma unroll
        for (int q = 0; q < 4; ++q) {
            p2 rev = xv[q] * splat(sRev[k * 4 + q]);   // half-angle in revolutions
            sh[q] = { __builtin_amdgcn_sinf(rev.x), __builtin_amdgcn_sinf(rev.y) };
            ch[q] = { __builtin_amdgcn_cosf(rev.x), __builtin_amdgcn_cosf(rev.y) };
        }
        #pragma unroll
        for (int q = 0; q < 4; ++q) {
            p2 c = ch[q], s = sh[q];
            const int zq = q >> 1;           // zang = (a0,a0,a1,a1)
            p2 cz = ch[zq], sz = sh[zq];
            p2 cc = c * c, ss = s * s, cs = c * s;
            // V = RZ(z)*RY(a)*RX(a), SU2 (alpha,beta)
            cp aV = { cc * cz + ss * sz, ss * cz - cc * sz };
            cp bV = { -(cs * (cz + sz)), -(cs * (cz - sz)) };
            float2 fa = sA[k][q][0], fb = sA[k][q][1];
            cp aA = { splat(fa.x), splat(fa.y) };
            cp bA = { splat(fb.x), splat(fb.y) };
            cp aM, bM;
            su2mulp(aA, bA, aV, bV, aM, bM); // M = A^(k) * V
            const int R = 8 >> q;
            #pragma unroll
            for (int g = 0; g < 8; ++g) {
                int low = g & (R - 1);
                int s0i = ((g - low) << 1) | low;
                int s1i = s0i + R;
                p2 p0r = prr[s0i], p0i = pii[s0i];
                p2 p1r = prr[s1i], p1i = pii[s1i];
                prr[s0i] = aM.re * p0r - aM.im * p0i + bM.re * p1r - bM.im * p1i;
                pii[s0i] = aM.re * p0i + aM.im * p0r + bM.re * p1i + bM.im * p1r;
                prr[s1i] = aM.re * p1r + aM.im * p1i - bM.re * p0r - bM.im * p0i;
                pii[s1i] = aM.re * p1i - aM.im * p1r - bM.re * p0i + bM.im * p0r;
            }
        }
        if (k < 2) {
            #pragma unroll
            for (int s = 0; s < 16; ++s) {
                if (czneg(s)) { prr[s] = -prr[s]; pii[s] = -pii[s]; }
            }
        }
    }

    // probabilities
    p2 p[16];
    #pragma unroll
    for (int s = 0; s < 16; ++s) p[s] = prr[s] * prr[s] + pii[s] * pii[s];

    // signed-tree reduction for the 4 Z expectations (qubit j = bit (3-j))
    p2 s01[8], d01[8];
    #pragma unroll
    for (int i = 0; i < 8; ++i) { s01[i] = p[2*i] + p[2*i+1]; d01[i] = p[2*i] - p[2*i+1]; }
    p2 o3 = ((d01[0] + d01[1]) + (d01[2] + d01[3])) + ((d01[4] + d01[5]) + (d01[6] + d01[7]));
    p2 s2v[4], d2v[4];
    #pragma unroll
    for (int j = 0; j < 4; ++j) { s2v[j] = s01[2*j] + s01[2*j+1]; d2v[j] = s01[2*j] - s01[2*j+1]; }
    p2 o2 = (d2v[0] + d2v[1]) + (d2v[2] + d2v[3]);
    p2 o1 = (s2v[0] - s2v[1]) + (s2v[2] - s2v[3]);
    p2 o0 = (s2v[0] + s2v[1]) - (s2v[2] + s2v[3]);

    float4 oa = { o0.x, o1.x, o2.x, o3.x };
    float4 ob = { o0.y, o1.y, o2.y, o3.y };
    ((float4*)out)[t] = oa;
    ((float4*)out)[t + HALF] = ob;
}

extern "C" void kernel_launch(void* const* d_in, const int* in_sizes, int n_in,
                              void* d_out, int out_size, void* d_ws, size_t ws_size,
                              hipStream_t stream) {
    const float* x     = (const float*)d_in[0];
    const float* theta = (const float*)d_in[1];
    const float* lmbd  = (const float*)d_in[2];
    float* out = (float*)d_out;
    vqc_kernel<<<dim3(HALF / BLOCK), dim3(BLOCK), 0, stream>>>(x, theta, lmbd, out);
}